// Round 1
// baseline (840.090 us; speedup 1.0000x reference)
//
#include <hip/hip_runtime.h>
#include <hip/hip_bf16.h>

// Problem constants (from reference)
#define BATCH 2048
#define POOL 32
#define SEL 16
#define PLEN 8
#define DIM 768
#define DIM4 (DIM / 4)          // 192 float4 per row
#define ROW4 (PLEN * DIM4)      // 1536 float4 per prompt
#define TILE4 (SEL * ROW4)      // 24576 float4 of selection per batch row
#define SIM_N (BATCH * SEL)     // 32768

// ---------------------------------------------------------------------------
// Kernel A: match[b][p] = cos-sim(query[b], key[p]); per-row top-16 rank via
// wave shuffles (lanes 0-31 = row b0, lanes 32-63 = row b1); count votes.
// ---------------------------------------------------------------------------
__global__ __launch_bounds__(256) void match_count_kernel(
    const float* __restrict__ q, const float* __restrict__ pk,
    float* __restrict__ match, int* __restrict__ counts) {
    int tid = blockIdx.x * 256 + threadIdx.x;   // 65536 threads = B*POOL
    int b = tid >> 5;
    int p = tid & 31;
    const float4* q4 = (const float4*)q + (size_t)b * DIM4;
    const float4* k4 = (const float4*)pk + (size_t)p * DIM4;
    float dot = 0.f, qq = 0.f, kk = 0.f;
#pragma unroll 4
    for (int i = 0; i < DIM4; ++i) {
        float4 a = q4[i];
        float4 c = k4[i];
        dot += a.x * c.x + a.y * c.y + a.z * c.z + a.w * c.w;
        qq  += a.x * a.x + a.y * a.y + a.z * a.z + a.w * a.w;
        kk  += c.x * c.x + c.y * c.y + c.z * c.z + c.w * c.w;
    }
    float m = dot / fmaxf(sqrtf(qq) * sqrtf(kk), 1e-8f);
    match[tid] = m;

    // rank of this entry within its row: #(v_j > v) + ties broken by lower idx
    int lane = threadIdx.x & 63;
    int half = lane & 32;   // which row within the wave
    int rank = 0;
    for (int i = 0; i < POOL; ++i) {
        float vm = __shfl(m, half | i, 64);   // lane (half|i) holds p == i
        rank += (vm > m || (vm == m && i < p)) ? 1 : 0;
    }

    __shared__ int cnt[POOL];
    if (threadIdx.x < POOL) cnt[threadIdx.x] = 0;
    __syncthreads();
    if (rank < SEL) atomicAdd(&cnt[p], 1);
    __syncthreads();
    if (threadIdx.x < POOL) atomicAdd(&counts[threadIdx.x], cnt[threadIdx.x]);
}

// ---------------------------------------------------------------------------
// Kernel B: single thread. mosts = top-16 of counts (count desc, index asc —
// jax.lax.top_k tie semantics). nonk = complement indices, ascending
// (stable argsort of 0/1 mask semantics).
// ---------------------------------------------------------------------------
__global__ void select_kernel(const int* __restrict__ counts,
                              int* __restrict__ mosts, int* __restrict__ nonk) {
    if (threadIdx.x == 0 && blockIdx.x == 0) {
        int c[POOL];
        for (int i = 0; i < POOL; ++i) c[i] = counts[i];
        int selrank[POOL];
        for (int i = 0; i < POOL; ++i) {
            int r = 0;
            for (int j = 0; j < POOL; ++j)
                r += (c[j] > c[i] || (c[j] == c[i] && j < i)) ? 1 : 0;
            selrank[i] = r;
            if (r < SEL) mosts[r] = i;
        }
        int np = 0;
        for (int i = 0; i < POOL; ++i)
            if (selrank[i] >= SEL) nonk[np++] = i;
    }
}

// ---------------------------------------------------------------------------
// Kernel C: sim[b][j] = match[b][mosts[j]]; unsim[b][j] = match[b][nonk[j]]
// ---------------------------------------------------------------------------
__global__ __launch_bounds__(256) void simuns_kernel(
    const float* __restrict__ match, const int* __restrict__ mosts,
    const int* __restrict__ nonk, float* __restrict__ out) {
    __shared__ int sm[SEL], sn[SEL];
    if (threadIdx.x < SEL) sm[threadIdx.x] = mosts[threadIdx.x];
    else if (threadIdx.x < 2 * SEL) sn[threadIdx.x - SEL] = nonk[threadIdx.x - SEL];
    __syncthreads();
    int tid = blockIdx.x * 256 + threadIdx.x;   // 65536 threads
    int b = tid >> 5;
    int j = tid & 31;
    if (j < SEL)
        out[b * SEL + j] = match[b * POOL + sm[j]];
    else
        out[SIM_N + b * SEL + (j - SEL)] = match[b * POOL + sn[j - SEL]];
}

// ---------------------------------------------------------------------------
// Kernel D: the 805 MB broadcast write. Each block owns 1024 consecutive
// float4 of selection; 24 blocks per batch row (TILE4 = 24576 = 24*1024).
// Reads hit L2 (prompts footprint 786 KB); writes stream to HBM.
// ---------------------------------------------------------------------------
__global__ __launch_bounds__(256) void sel_write_kernel(
    const float4* __restrict__ prompts4, const int* __restrict__ mosts,
    float4* __restrict__ out4) {
    __shared__ int sm[SEL];
    if (threadIdx.x < SEL) sm[threadIdx.x] = mosts[threadIdx.x];
    __syncthreads();
    size_t base = (size_t)blockIdx.x * 1024;
    int r4base = (blockIdx.x % 24) * 1024;   // offset within the 24576-f4 tile
#pragma unroll
    for (int k = 0; k < 4; ++k) {
        int idx = r4base + threadIdx.x + k * 256;
        int j = idx / ROW4;                  // which of the 16 selected prompts
        int rem = idx - j * ROW4;
        out4[base + threadIdx.x + k * 256] = prompts4[(size_t)sm[j] * ROW4 + rem];
    }
}

// ---------------------------------------------------------------------------
extern "C" void kernel_launch(void* const* d_in, const int* in_sizes, int n_in,
                              void* d_out, int out_size, void* d_ws, size_t ws_size,
                              hipStream_t stream) {
    const float* query   = (const float*)d_in[0];   // [2048, 768]
    const float* pkey    = (const float*)d_in[1];   // [32, 768]
    const float* prompts = (const float*)d_in[2];   // [32, 8, 768]
    float* out = (float*)d_out;

    // workspace layout
    float* match = (float*)d_ws;                          // 65536 f32 = 256 KiB
    int* counts  = (int*)((char*)d_ws + 65536 * 4);       // 32 i32
    int* mosts   = counts + POOL;                         // 16 i32
    int* nonk    = mosts + SEL;                           // 16 i32

    hipMemsetAsync(counts, 0, POOL * sizeof(int), stream);

    match_count_kernel<<<(BATCH * POOL) / 256, 256, 0, stream>>>(query, pkey, match, counts);
    select_kernel<<<1, 64, 0, stream>>>(counts, mosts, nonk);
    simuns_kernel<<<(BATCH * POOL) / 256, 256, 0, stream>>>(match, mosts, nonk, out);

    float4* sel_out = (float4*)(out + 2 * SIM_N);   // selection starts at float 65536
    sel_write_kernel<<<BATCH * 24, 256, 0, stream>>>(
        (const float4*)prompts, mosts, sel_out);
}